// Round 9
// baseline (89.518 us; speedup 1.0000x reference)
//
#include <hip/hip_runtime.h>

// Problem constants (KANLayer): B=1024, I=128, O=128, H=5
#define Bsz 1024
#define Isz 128
#define Osz 128
#define Hsz 5
#define GB 32    // batches per block (16.5 KB LDS)
#define NG (Bsz / GB)
#define UPAIR 2  // v2f batch-pairs in flight (4 batches); ~95 live VGPRs < 128

typedef float v2f __attribute__((ext_vector_type(2)));
__device__ __forceinline__ v2f s2(float v) { return (v2f){v, v}; }

// ---------------------------------------------------------------------------
// DPP wave64 sum -> lane 63. All VALU (v_add_f32_dpp), zero DS-pipe.
// ---------------------------------------------------------------------------
template <int CTRL>
__device__ __forceinline__ float dpp_add(float s) {
    int t = __builtin_amdgcn_update_dpp(0, __builtin_bit_cast(int, s),
                                        CTRL, 0xf, 0xf, true);
    return s + __builtin_bit_cast(float, t);
}
__device__ __forceinline__ float wave_sum64_lane63(float s) {
    s = dpp_add<0xB1>(s);    // quad_perm xor1
    s = dpp_add<0x4E>(s);    // quad_perm xor2
    s = dpp_add<0x141>(s);   // row_half_mirror (xor 4)
    s = dpp_add<0x140>(s);   // row_mirror      (xor 8)
    s = dpp_add<0x142>(s);   // row_bcast:15
    s = dpp_add<0x143>(s);   // row_bcast:31
    return s;                // lane 63 = full sum
}
__device__ __forceinline__ float lane63(float s) {
    return __builtin_bit_cast(float,
        __builtin_amdgcn_readlane(__builtin_bit_cast(int, s), 63));
}

// ---------------------------------------------------------------------------
// Edge-stationary kernel, packed-fp32 math.
// Thread <-> one edge (o,i); 46 params in VGPRs (gathered once). Batches
// stream through LDS in v2f PAIRS so layer math lowers to v_pk_fma_f32 /
// v_pk_mul_f32 (scalar operands broadcast free via op_sel); only the lrelu
// maxes scalarize (no v_pk_max_f32 on CDNA). ~85 inst/pair vs 130 scalar.
// launch_bounds(256,4): VGPR quantum steps at 64/128 (m69) -> 4 waves/SIMD
// for any VGPR in (64,128]; don't squeeze the allocator below that.
// Block = 4 waves = 2 o's x 128 i; grid 2048 blocks; out written once.
// ---------------------------------------------------------------------------
__global__ __launch_bounds__(256, 4)
void kan_kernel(const float* __restrict__ x,
                const float* __restrict__ W1, const float* __restrict__ B1,
                const float* __restrict__ W2, const float* __restrict__ B2,
                const float* __restrict__ W3, const float* __restrict__ B3,
                float* __restrict__ out) {
    __shared__ float xs[GB * Isz];        // 16 KB: x[b0:b0+32][0:128]
    __shared__ float partial[4 * GB];     // 512 B: per-wave reduced rows

    const int tid = threadIdx.x;
    const int ob  = blockIdx.x & 63;      // o-pair index (fastest)
    const int g   = blockIdx.x >> 6;      // batch group 0..31
    const int b0  = g * GB;
    const int w   = tid >> 6;             // wave 0..3
    const int l   = tid & 63;             // lane
    const int o   = 2 * ob + (w >> 1);
    const int i   = 64 * (w & 1) + l;     // i-half per wave
    const int e   = o * Isz + i;

    // --- stage x tile (coalesced float4, once) ---
    {
        const float4* xg = (const float4*)(x + (size_t)b0 * Isz);
        float4* xs4 = (float4*)xs;
        #pragma unroll
        for (int j = 0; j < (GB * Isz / 4) / 256; ++j)   // 4 iters
            xs4[tid + 256 * j] = xg[tid + 256 * j];
    }

    // --- my edge's 46 params -> VGPRs, gathered once ---
    float w1[Hsz], b1[Hsz], w2[Hsz * Hsz], b2[Hsz], w3[Hsz];
    #pragma unroll
    for (int h = 0; h < Hsz; ++h) {
        w1[h] = W1[(size_t)e * Hsz + h];
        b1[h] = B1[(size_t)e * Hsz + h];
        b2[h] = B2[(size_t)e * Hsz + h];
        w3[h] = W3[(size_t)e * Hsz + h];
    }
    #pragma unroll
    for (int j = 0; j < Hsz * Hsz; ++j) w2[j] = W2[(size_t)e * Hsz * Hsz + j];

    // batch-invariant b3 term: wave-reduced once
    const float s3 = lane63(wave_sum64_lane63(B3[e]));

    __syncthreads();

    float res = 0.0f;   // out-partial for batch b0+l (l < GB), this i-half

    #pragma unroll
    for (int bl = 0; bl < GB; bl += 2 * UPAIR) {
        v2f y[UPAIR];
        #pragma unroll
        for (int u = 0; u < UPAIR; ++u) {
            // adjacent batches, 512 B apart in LDS -> ds_read2_b32 candidate
            v2f a;
            a.x = xs[(bl + 2 * u + 0) * Isz + i];
            a.y = xs[(bl + 2 * u + 1) * Isz + i];

            // layer 1: scalar -> H, leaky_relu(0.01)   [v_pk_fma + v_pk_mul + 2x v_max]
            v2f h1[Hsz];
            #pragma unroll
            for (int h = 0; h < Hsz; ++h) {
                v2f t = __builtin_elementwise_fma(a, s2(w1[h]), s2(b1[h]));
                h1[h] = __builtin_elementwise_max(t, t * 0.01f);
            }
            // layer 2 (H->H, lrelu) + layer 3 (H->1, b3 hoisted)
            v2f yy = s2(0.0f);
            #pragma unroll
            for (int k = 0; k < Hsz; ++k) {
                v2f s = s2(b2[k]);
                #pragma unroll
                for (int h = 0; h < Hsz; ++h)
                    s = __builtin_elementwise_fma(h1[h], s2(w2[k * Hsz + h]), s);
                s = __builtin_elementwise_max(s, s * 0.01f);
                yy = __builtin_elementwise_fma(s, s2(w3[k]), yy);
            }
            y[u] = yy;
        }

        // DPP reduce each half; park lane-63 totals in lanes bl+2u, bl+2u+1.
        #pragma unroll
        for (int u = 0; u < UPAIR; ++u) {
            const float t0 = lane63(wave_sum64_lane63(y[u].x));
            const float t1 = lane63(wave_sum64_lane63(y[u].y));
            if (l == bl + 2 * u + 0) res = t0;
            if (l == bl + 2 * u + 1) res = t1;
        }
    }

    if (l < GB) partial[w * GB + l] = res + s3;
    __syncthreads();

    // combine i-half waves and store: 64 outputs per block, each written once
    if (tid < 2 * GB) {
        const int bl = tid & (GB - 1);
        const int oo = tid >> 5;
        const float v = partial[(2 * oo) * GB + bl] + partial[(2 * oo + 1) * GB + bl];
        out[(size_t)(b0 + bl) * Osz + (2 * ob + oo)] = v;
    }
}

extern "C" void kernel_launch(void* const* d_in, const int* in_sizes, int n_in,
                              void* d_out, int out_size, void* d_ws, size_t ws_size,
                              hipStream_t stream) {
    const float* x  = (const float*)d_in[0];
    const float* W1 = (const float*)d_in[1];
    const float* B1 = (const float*)d_in[2];
    const float* W2 = (const float*)d_in[3];
    const float* B2 = (const float*)d_in[4];
    const float* W3 = (const float*)d_in[5];
    const float* B3 = (const float*)d_in[6];
    float* out = (float*)d_out;

    const dim3 grid((Osz / 2) * NG);   // 64 o-pairs x 32 batch groups = 2048 blocks
    kan_kernel<<<grid, dim3(256), 0, stream>>>(x, W1, B1, W2, B2, W3, B3, out);
}